// Round 3
// baseline (128.654 us; speedup 1.0000x reference)
//
#include <hip/hip_runtime.h>
#include <math.h>

#define Hh 512
#define Ww 512
#define Bb 4
#define Ee 32
#define PLANE (Hh*Ww)        // 262144
#define NOFF 9

// ws layout (float indices)
#define WS_BLUR   0          // 262144 floats: blurred raw
#define WS_MIN    524304     // 16 uints: per-offset min bits
#define WS_MAX    524320     // 16 uints: per-offset max bits
#define WS_ACC    524336     // double accumulator (float idx, 8B-aligned)
#define WS_CNT    524338     // uint: finished-block counter

__device__ __constant__ int d_OH[NOFF] = {0,-1,-1,0,-2,-2,0,-3,-3};
__device__ __constant__ int d_OW[NOFF] = {-1,0,-1,-2,0,-2,-3,0,-3};

// ---- fused 2D gaussian blur (sigma=1.2, r=5, edge-clamped), 32x32 tiles + halo
#define TS 32
#define HALO 5
__global__ __launch_bounds__(256) void k_blur(const float* __restrict__ raw,
                                              float* __restrict__ ws){
    __shared__ float sraw[TS+2*HALO][TS+2*HALO+1];  // 42 x 43
    __shared__ float shb [TS][TS+2*HALO+1];         // 32 x 43
    int tx = blockIdx.x & 15, ty = blockIdx.x >> 4;
    int r0 = ty*TS - HALO, c0 = tx*TS - HALO;

    // gaussian weights in fp64 (matches numpy), per-thread
    double kd[11], s = 0.0;
    #pragma unroll
    for (int i = 0; i < 11; i++){
        double x = (double)(i - 5) / 1.2;
        kd[i] = exp(-0.5 * x * x);
        s += kd[i];
    }
    float w[11];
    #pragma unroll
    for (int i = 0; i < 11; i++) w[i] = (float)(kd[i] / s);

    // load raw tile + halo, edge-clamped
    for (int t = threadIdx.x; t < 42*42; t += 256){
        int rr = t / 42, cc = t - rr*42;
        int gr = min(max(r0+rr, 0), Hh-1);
        int gc = min(max(c0+cc, 0), Ww-1);
        sraw[rr][cc] = raw[gr*Ww + gc];
    }
    __syncthreads();
    // blur along H
    for (int t = threadIdx.x; t < TS*42; t += 256){
        int rr = t / 42, cc = t - rr*42;
        float a = 0.f;
        #pragma unroll
        for (int i = 0; i < 11; i++) a += w[i] * sraw[rr+i][cc];
        shb[rr][cc] = a;
    }
    __syncthreads();
    // blur along W, write out
    for (int t = threadIdx.x; t < TS*TS; t += 256){
        int rr = t >> 5, cc = t & 31;
        float a = 0.f;
        #pragma unroll
        for (int i = 0; i < 11; i++) a += w[i] * shb[rr][cc+i];
        ws[WS_BLUR + (ty*TS+rr)*Ww + (tx*TS+cc)] = a;
    }
    // init reduction slots (used by later kernels this call)
    if (blockIdx.x == 0){
        if (threadIdx.x < 16){
            ((unsigned int*)(ws + WS_MIN))[threadIdx.x] = 0x7F800000u;
            ((unsigned int*)(ws + WS_MAX))[threadIdx.x] = 0u;
        }
        if (threadIdx.x == 0){
            *(double*)(ws + WS_ACC) = 0.0;
            *(unsigned int*)(ws + WS_CNT) = 0u;
        }
    }
}

// per-offset min/max of d_i = |blur - rolled blur|
__global__ void k_minmax(float* __restrict__ ws){
    int idx = blockIdx.x * 512 + threadIdx.x;
    int h = idx >> 9, w = idx & 511;
    float bc = ws[WS_BLUR + idx];
    int lane = threadIdx.x & 63, wv = threadIdx.x >> 6;
    __shared__ float smn[8 * NOFF], smx[8 * NOFF];
    #pragma unroll
    for (int i = 0; i < NOFF; i++){
        int hn = (h + d_OH[i]) & (Hh-1);
        int wn = (w + d_OW[i]) & (Ww-1);
        float d = fabsf(bc - ws[WS_BLUR + hn * Ww + wn]);
        float mnv = d, mxv = d;
        for (int s = 32; s; s >>= 1){
            mnv = fminf(mnv, __shfl_xor(mnv, s));
            mxv = fmaxf(mxv, __shfl_xor(mxv, s));
        }
        if (lane == 0){ smn[wv * NOFF + i] = mnv; smx[wv * NOFF + i] = mxv; }
    }
    __syncthreads();
    if (threadIdx.x < NOFF){
        float mnv = smn[threadIdx.x], mxv = smx[threadIdx.x];
        for (int v = 1; v < 8; v++){
            mnv = fminf(mnv, smn[v * NOFF + threadIdx.x]);
            mxv = fmaxf(mxv, smx[v * NOFF + threadIdx.x]);
        }
        atomicMin((unsigned int*)(ws + WS_MIN) + threadIdx.x, __float_as_uint(mnv));
        atomicMax((unsigned int*)(ws + WS_MAX) + threadIdx.x, __float_as_uint(mxv));
    }
}

// fused loss: each thread owns 4 consecutive pixels (float4-aligned).
// per px: sum_i c_i(1-dot_i) = csum - sum_e E[e]*(sum_i c_i*T[e,nbr_i])
__global__ __launch_bounds__(256, 4)
void k_main(const float* __restrict__ E, const float* __restrict__ T,
            const float* __restrict__ mask, float* __restrict__ ws,
            float* __restrict__ out){
    int g = blockIdx.x * 256 + threadIdx.x;   // 0..262143
    int b  = g >> 16;
    int hr = (g >> 7) & 511;
    int wq = g & 127;
    int c0 = wq << 2;
    int cl = (c0 - 4) & 511;
    int rr1 = (hr-1)&511, rr2 = (hr-2)&511, rr3 = (hr-3)&511;
    int pix = hr * Ww + c0;

    int ro[4] = { pix,           rr1*Ww + c0, rr2*Ww + c0, rr3*Ww + c0 };
    int lo[4] = { hr*Ww + cl,    rr1*Ww + cl, rr2*Ww + cl, rr3*Ww + cl };

    // ---- blur neighborhood -> per-pixel coefficients c[j][i]
    const float* bl = ws + WS_BLUR;
    float tb[4][8];
    #pragma unroll
    for (int r = 0; r < 4; r++){
        float4 l4 = *(const float4*)(bl + lo[r]);
        float4 o4 = *(const float4*)(bl + ro[r]);
        tb[r][0]=l4.x; tb[r][1]=l4.y; tb[r][2]=l4.z; tb[r][3]=l4.w;
        tb[r][4]=o4.x; tb[r][5]=o4.y; tb[r][6]=o4.z; tb[r][7]=o4.w;
    }
    const unsigned int* mnb = (const unsigned int*)(ws + WS_MIN);
    const unsigned int* mxb = (const unsigned int*)(ws + WS_MAX);
    float mn[NOFF], inv[NOFF];
    #pragma unroll
    for (int i = 0; i < NOFF; i++){
        mn[i]  = __uint_as_float(mnb[i]);
        inv[i] = 1.f / (__uint_as_float(mxb[i]) - mn[i]);
    }
    float c[4][NOFF];
    float acc[4];   // init with csum, subtract dot terms
    #pragma unroll
    for (int j = 0; j < 4; j++){
        float bc = tb[0][4+j];
        float d[NOFF];
        d[0] = fabsf(bc - tb[0][3+j]);
        d[1] = fabsf(bc - tb[1][4+j]);
        d[2] = fabsf(bc - tb[1][3+j]);
        d[3] = fabsf(bc - tb[0][2+j]);
        d[4] = fabsf(bc - tb[2][4+j]);
        d[5] = fabsf(bc - tb[2][2+j]);
        d[6] = fabsf(bc - tb[0][1+j]);
        d[7] = fabsf(bc - tb[3][4+j]);
        d[8] = fabsf(bc - tb[3][1+j]);
        acc[j] = 0.f;
        float4 dummy;
        #pragma unroll
        for (int i = 0; i < NOFF; i++){
            float a = (d[i] - mn[i]) * inv[i];
            float mv = ((const float*)(mask + i * PLANE + pix))[j];
            c[j][i] = mv * (0.5f - a);
            acc[j] += c[j][i];
        }
        (void)dummy;
    }

    // ---- e-loop: 9 dwordx4 loads per iteration, all independent
    const float* Eb = E + (size_t)b * Ee * PLANE + pix;
    const float* Tb = T + (size_t)b * Ee * PLANE;
    for (int e = 0; e < Ee; e++){
        const float* Tp = Tb + (size_t)e * PLANE;
        float4 ev4 = *(const float4*)(Eb + (size_t)e * PLANE);
        float ev[4] = {ev4.x, ev4.y, ev4.z, ev4.w};
        float t[4][8];
        #pragma unroll
        for (int r = 0; r < 4; r++){
            float4 l4 = *(const float4*)(Tp + lo[r]);
            float4 o4 = *(const float4*)(Tp + ro[r]);
            t[r][0]=l4.x; t[r][1]=l4.y; t[r][2]=l4.z; t[r][3]=l4.w;
            t[r][4]=o4.x; t[r][5]=o4.y; t[r][6]=o4.z; t[r][7]=o4.w;
        }
        #pragma unroll
        for (int j = 0; j < 4; j++){
            float s =        c[j][0] * t[0][3+j];
            s = fmaf(c[j][1], t[1][4+j], s);
            s = fmaf(c[j][2], t[1][3+j], s);
            s = fmaf(c[j][3], t[0][2+j], s);
            s = fmaf(c[j][4], t[2][4+j], s);
            s = fmaf(c[j][5], t[2][2+j], s);
            s = fmaf(c[j][6], t[0][1+j], s);
            s = fmaf(c[j][7], t[3][4+j], s);
            s = fmaf(c[j][8], t[3][1+j], s);
            acc[j] = fmaf(-ev[j], s, acc[j]);   // free input modifier
        }
    }

    float part = acc[0] + acc[1] + acc[2] + acc[3];

    // block reduction (4 waves)
    for (int s = 32; s; s >>= 1) part += __shfl_xor(part, s);
    __shared__ float sp[4];
    int lane = threadIdx.x & 63, wv = threadIdx.x >> 6;
    if (lane == 0) sp[wv] = part;
    __syncthreads();
    if (threadIdx.x == 0){
        float bs = sp[0] + sp[1] + sp[2] + sp[3];
        double* accp = (double*)(ws + WS_ACC);
        atomicAdd(accp, (double)bs);
        __threadfence();
        unsigned int done = atomicAdd((unsigned int*)(ws + WS_CNT), 1u);
        if (done == gridDim.x - 1){
            double v = atomicAdd(accp, 0.0);   // coherent read of final sum
            out[0] = (float)(v / (double)((size_t)Bb * PLANE));
        }
    }
}

extern "C" void kernel_launch(void* const* d_in, const int* in_sizes, int n_in,
                              void* d_out, int out_size, void* d_ws, size_t ws_size,
                              hipStream_t stream) {
    const float* embeds = (const float*)d_in[0];   // [4,32,512,512]
    const float* tf     = (const float*)d_in[1];   // [4,32,512,512]
    const float* raw    = (const float*)d_in[2];   // [1,1,512,512]
    const float* mask   = (const float*)d_in[3];   // [1,9,512,512]
    float* ws  = (float*)d_ws;
    float* out = (float*)d_out;

    k_blur  <<<256, 256, 0, stream>>>(raw, ws);
    k_minmax<<<PLANE/512, 512, 0, stream>>>(ws);
    k_main  <<<PLANE*Bb/4/256, 256, 0, stream>>>(embeds, tf, mask, ws, out);
}

// Round 4
// 105.726 us; speedup vs baseline: 1.2169x; 1.2169x over previous
//
#include <hip/hip_runtime.h>
#include <math.h>

#define Hh 512
#define Ww 512
#define Bb 4
#define Ee 32
#define PLANE (Hh*Ww)        // 262144
#define NOFF 9

// ws layout (float indices)
#define WS_BLUR   0          // 262144 floats: blurred raw
#define WS_MIN    524304     // 16 uints: per-offset min bits
#define WS_MAX    524320     // 16 uints: per-offset max bits
#define WS_ACC    524336     // double accumulator (8B-aligned)
#define WS_CNT    524338     // uint: finished-block counter

__device__ __constant__ int d_OH[NOFF] = {0,-1,-1,0,-2,-2,0,-3,-3};
__device__ __constant__ int d_OW[NOFF] = {-1,0,-1,-2,0,-2,-3,0,-3};

// ---- fused 2D gaussian blur (sigma=1.2, r=5, edge-clamped), 32x32 tiles + halo
#define TS 32
#define HALO 5
__global__ __launch_bounds__(256) void k_blur(const float* __restrict__ raw,
                                              float* __restrict__ ws){
    __shared__ float sraw[TS+2*HALO][TS+2*HALO+1];  // 42 x 43
    __shared__ float shb [TS][TS+2*HALO+1];         // 32 x 43
    int tx = blockIdx.x & 15, ty = blockIdx.x >> 4;
    int r0 = ty*TS - HALO, c0 = tx*TS - HALO;

    double kd[11], s = 0.0;
    #pragma unroll
    for (int i = 0; i < 11; i++){
        double x = (double)(i - 5) / 1.2;
        kd[i] = exp(-0.5 * x * x);
        s += kd[i];
    }
    float w[11];
    #pragma unroll
    for (int i = 0; i < 11; i++) w[i] = (float)(kd[i] / s);

    for (int t = threadIdx.x; t < 42*42; t += 256){
        int rr = t / 42, cc = t - rr*42;
        int gr = min(max(r0+rr, 0), Hh-1);
        int gc = min(max(c0+cc, 0), Ww-1);
        sraw[rr][cc] = raw[gr*Ww + gc];
    }
    __syncthreads();
    for (int t = threadIdx.x; t < TS*42; t += 256){
        int rr = t / 42, cc = t - rr*42;
        float a = 0.f;
        #pragma unroll
        for (int i = 0; i < 11; i++) a += w[i] * sraw[rr+i][cc];
        shb[rr][cc] = a;
    }
    __syncthreads();
    for (int t = threadIdx.x; t < TS*TS; t += 256){
        int rr = t >> 5, cc = t & 31;
        float a = 0.f;
        #pragma unroll
        for (int i = 0; i < 11; i++) a += w[i] * shb[rr][cc+i];
        ws[WS_BLUR + (ty*TS+rr)*Ww + (tx*TS+cc)] = a;
    }
    if (blockIdx.x == 0){
        if (threadIdx.x < 16){
            ((unsigned int*)(ws + WS_MIN))[threadIdx.x] = 0x7F800000u;
            ((unsigned int*)(ws + WS_MAX))[threadIdx.x] = 0u;
        }
        if (threadIdx.x == 0){
            *(double*)(ws + WS_ACC) = 0.0;
            *(unsigned int*)(ws + WS_CNT) = 0u;
        }
    }
}

// per-offset min/max of d_i = |blur - rolled blur|
__global__ void k_minmax(float* __restrict__ ws){
    int idx = blockIdx.x * 512 + threadIdx.x;
    int h = idx >> 9, w = idx & 511;
    float bc = ws[WS_BLUR + idx];
    int lane = threadIdx.x & 63, wv = threadIdx.x >> 6;
    __shared__ float smn[8 * NOFF], smx[8 * NOFF];
    #pragma unroll
    for (int i = 0; i < NOFF; i++){
        int hn = (h + d_OH[i]) & (Hh-1);
        int wn = (w + d_OW[i]) & (Ww-1);
        float d = fabsf(bc - ws[WS_BLUR + hn * Ww + wn]);
        float mnv = d, mxv = d;
        for (int s = 32; s; s >>= 1){
            mnv = fminf(mnv, __shfl_xor(mnv, s));
            mxv = fmaxf(mxv, __shfl_xor(mxv, s));
        }
        if (lane == 0){ smn[wv * NOFF + i] = mnv; smx[wv * NOFF + i] = mxv; }
    }
    __syncthreads();
    if (threadIdx.x < NOFF){
        float mnv = smn[threadIdx.x], mxv = smx[threadIdx.x];
        for (int v = 1; v < 8; v++){
            mnv = fminf(mnv, smn[v * NOFF + threadIdx.x]);
            mxv = fmaxf(mxv, smx[v * NOFF + threadIdx.x]);
        }
        atomicMin((unsigned int*)(ws + WS_MIN) + threadIdx.x, __float_as_uint(mnv));
        atomicMax((unsigned int*)(ws + WS_MAX) + threadIdx.x, __float_as_uint(mxv));
    }
}

// 9 float4 tf loads + 1 embed float4, software-pipelined one tile ahead
struct TT { float4 l0,o0,l1,o1,l2,o2,l3,o3, ev; };

// fused loss: 512-thread blocks, block = 4 full rows of one batch image.
// per px: sum_i c_i(1-dot_i) = csum - sum_e E[e]*(sum_i c_i*T[e,nbr_i])
__global__ __launch_bounds__(512)
void k_main(const float* __restrict__ E, const float* __restrict__ T,
            const float* __restrict__ mask, float* __restrict__ ws,
            float* __restrict__ out){
    int blk = blockIdx.x;                 // 0..511
    int bb  = blk >> 7;                   // batch (block-uniform -> SGPR base)
    int row4 = (blk & 127) << 2;
    int rq  = threadIdx.x >> 7;           // 0..3
    int wq  = threadIdx.x & 127;
    int hr  = row4 + rq;
    int c0  = wq << 2;
    int cl  = (c0 - 4) & 511;
    int rr1 = (hr-1)&511, rr2 = (hr-2)&511, rr3 = (hr-3)&511;
    int pix = hr * Ww + c0;

    int ro0 = pix,         lo0 = hr*Ww + cl;
    int ro1 = rr1*Ww + c0, lo1 = rr1*Ww + cl;
    int ro2 = rr2*Ww + c0, lo2 = rr2*Ww + cl;
    int ro3 = rr3*Ww + c0, lo3 = rr3*Ww + cl;

    // ---- blur neighborhood -> per-pixel coefficients c[j][i]
    const float* bl = ws + WS_BLUR;
    float tb[4][8];
    {
        float4 v;
        v = *(const float4*)(bl + lo0); tb[0][0]=v.x; tb[0][1]=v.y; tb[0][2]=v.z; tb[0][3]=v.w;
        v = *(const float4*)(bl + ro0); tb[0][4]=v.x; tb[0][5]=v.y; tb[0][6]=v.z; tb[0][7]=v.w;
        v = *(const float4*)(bl + lo1); tb[1][0]=v.x; tb[1][1]=v.y; tb[1][2]=v.z; tb[1][3]=v.w;
        v = *(const float4*)(bl + ro1); tb[1][4]=v.x; tb[1][5]=v.y; tb[1][6]=v.z; tb[1][7]=v.w;
        v = *(const float4*)(bl + lo2); tb[2][0]=v.x; tb[2][1]=v.y; tb[2][2]=v.z; tb[2][3]=v.w;
        v = *(const float4*)(bl + ro2); tb[2][4]=v.x; tb[2][5]=v.y; tb[2][6]=v.z; tb[2][7]=v.w;
        v = *(const float4*)(bl + lo3); tb[3][0]=v.x; tb[3][1]=v.y; tb[3][2]=v.z; tb[3][3]=v.w;
        v = *(const float4*)(bl + ro3); tb[3][4]=v.x; tb[3][5]=v.y; tb[3][6]=v.z; tb[3][7]=v.w;
    }
    const unsigned int* mnb = (const unsigned int*)(ws + WS_MIN);
    const unsigned int* mxb = (const unsigned int*)(ws + WS_MAX);
    float mn[NOFF], inv[NOFF];
    #pragma unroll
    for (int i = 0; i < NOFF; i++){
        mn[i]  = __uint_as_float(mnb[i]);
        inv[i] = 1.f / (__uint_as_float(mxb[i]) - mn[i]);
    }
    float c[4][NOFF];
    float acc[4];
    #pragma unroll
    for (int j = 0; j < 4; j++){
        float bc = tb[0][4+j];
        float d[NOFF];
        d[0] = fabsf(bc - tb[0][3+j]);
        d[1] = fabsf(bc - tb[1][4+j]);
        d[2] = fabsf(bc - tb[1][3+j]);
        d[3] = fabsf(bc - tb[0][2+j]);
        d[4] = fabsf(bc - tb[2][4+j]);
        d[5] = fabsf(bc - tb[2][2+j]);
        d[6] = fabsf(bc - tb[0][1+j]);
        d[7] = fabsf(bc - tb[3][4+j]);
        d[8] = fabsf(bc - tb[3][1+j]);
        acc[j] = 0.f;
        #pragma unroll
        for (int i = 0; i < NOFF; i++){
            float a = (d[i] - mn[i]) * inv[i];
            float mv = ((const float*)(mask + i * PLANE + pix))[j];
            c[j][i] = mv * (0.5f - a);
            acc[j] += c[j][i];
        }
    }

    // SGPR bases (bb is block-uniform by construction)
    const float* Tb = T + (size_t)bb * Ee * PLANE;
    const float* Eb = E + (size_t)bb * Ee * PLANE + pix;

    auto LD = [&](TT& d, int e){
        const float* Tp = Tb + (size_t)e * PLANE;
        d.l0 = *(const float4*)(Tp + lo0); d.o0 = *(const float4*)(Tp + ro0);
        d.l1 = *(const float4*)(Tp + lo1); d.o1 = *(const float4*)(Tp + ro1);
        d.l2 = *(const float4*)(Tp + lo2); d.o2 = *(const float4*)(Tp + ro2);
        d.l3 = *(const float4*)(Tp + lo3); d.o3 = *(const float4*)(Tp + ro3);
        d.ev = *(const float4*)(Eb + (size_t)e * PLANE);
    };
    auto CMP = [&](const TT& t){
        float t0[8] = {t.l0.x,t.l0.y,t.l0.z,t.l0.w, t.o0.x,t.o0.y,t.o0.z,t.o0.w};
        float t1[8] = {t.l1.x,t.l1.y,t.l1.z,t.l1.w, t.o1.x,t.o1.y,t.o1.z,t.o1.w};
        float t2[8] = {t.l2.x,t.l2.y,t.l2.z,t.l2.w, t.o2.x,t.o2.y,t.o2.z,t.o2.w};
        float t3[8] = {t.l3.x,t.l3.y,t.l3.z,t.l3.w, t.o3.x,t.o3.y,t.o3.z,t.o3.w};
        float ev[4] = {t.ev.x, t.ev.y, t.ev.z, t.ev.w};
        #pragma unroll
        for (int j = 0; j < 4; j++){
            float s =        c[j][0] * t0[3+j];
            s = fmaf(c[j][1], t1[4+j], s);
            s = fmaf(c[j][2], t1[3+j], s);
            s = fmaf(c[j][3], t0[2+j], s);
            s = fmaf(c[j][4], t2[4+j], s);
            s = fmaf(c[j][5], t2[2+j], s);
            s = fmaf(c[j][6], t0[1+j], s);
            s = fmaf(c[j][7], t3[4+j], s);
            s = fmaf(c[j][8], t3[1+j], s);
            acc[j] = fmaf(-ev[j], s, acc[j]);
        }
    };

    // software pipeline, 1 tile lookahead, manually unrolled x2 (no reg copies)
    TT ta, tc;
    LD(ta, 0);
    #pragma unroll 1
    for (int e = 0; e < Ee-2; e += 2){
        LD(tc, e+1);
        CMP(ta);
        LD(ta, e+2);
        CMP(tc);
    }
    LD(tc, Ee-1);
    CMP(ta);
    CMP(tc);

    float part = acc[0] + acc[1] + acc[2] + acc[3];

    // block reduction (8 waves)
    for (int s = 32; s; s >>= 1) part += __shfl_xor(part, s);
    __shared__ float sp[8];
    int lane = threadIdx.x & 63, wv = threadIdx.x >> 6;
    if (lane == 0) sp[wv] = part;
    __syncthreads();
    if (threadIdx.x == 0){
        float bs = 0.f;
        #pragma unroll
        for (int v = 0; v < 8; v++) bs += sp[v];
        double* accp = (double*)(ws + WS_ACC);
        atomicAdd(accp, (double)bs);
        __threadfence();
        unsigned int done = atomicAdd((unsigned int*)(ws + WS_CNT), 1u);
        if (done == gridDim.x - 1){
            double v = atomicAdd(accp, 0.0);
            out[0] = (float)(v / (double)((size_t)Bb * PLANE));
        }
    }
}

extern "C" void kernel_launch(void* const* d_in, const int* in_sizes, int n_in,
                              void* d_out, int out_size, void* d_ws, size_t ws_size,
                              hipStream_t stream) {
    const float* embeds = (const float*)d_in[0];   // [4,32,512,512]
    const float* tf     = (const float*)d_in[1];   // [4,32,512,512]
    const float* raw    = (const float*)d_in[2];   // [1,1,512,512]
    const float* mask   = (const float*)d_in[3];   // [1,9,512,512]
    float* ws  = (float*)d_ws;
    float* out = (float*)d_out;

    k_blur  <<<256, 256, 0, stream>>>(raw, ws);
    k_minmax<<<PLANE/512, 512, 0, stream>>>(ws);
    k_main  <<<512, 512, 0, stream>>>(embeds, tf, mask, ws, out);
}